// Round 1
// baseline (815.423 us; speedup 1.0000x reference)
//
#include <hip/hip_runtime.h>
#include <math.h>

#define NN 50000
#define FD 8
#define TD 12
#define HD 64
#define FT 96            // FD*TD floats per node
#define EE 1600000

// Workspace layout (floats):
//   deg   [0, NN)
//   dinv  [NN, 2*NN)
//   coeff [2*NN, 2*NN+EE)
//   agg   [2*NN+EE, 2*NN+EE+NN*FT)
//   fused [.., +1164): Wzz(512) Whh(512) bzz(64) bhh(64) probs(12)
// total ≈ 26 MB
#define OFF_DEG   0
#define OFF_DINV  (NN)
#define OFF_COEFF (2*NN)
#define OFF_AGG   (2*NN + EE)
#define OFF_FUSED (OFF_AGG + NN*FT)

__global__ void k_precompute(const float* __restrict__ conv_w,
                             const float* __restrict__ conv_b,
                             const float* __restrict__ lin_w,
                             const float* __restrict__ lin_b,
                             const float* __restrict__ attention,
                             float* __restrict__ fused) {
    int tid = threadIdx.x;
    // Wzz (idx 0..511): f,h -> sum_k conv_w[f][k]   * lin_w[0][k][h]
    // Whh (idx 512..1023):     sum_k conv_w[f][128+k]* lin_w[2][k][h]
    for (int idx = tid; idx < 1024; idx += blockDim.x) {
        int sel = idx >> 9;
        int f = (idx & 511) >> 6;
        int h = idx & 63;
        const float* cw = conv_w + f * 192 + (sel ? 128 : 0);
        const float* lw = lin_w + (sel ? 2 * 128 * 64 : 0) + h;
        float s = 0.f;
        for (int k = 0; k < 64; ++k) s += cw[k] * lw[k * 64];
        fused[idx] = s;
    }
    // bzz (1024..1087), bhh (1088..1151)
    for (int idx = tid; idx < 128; idx += blockDim.x) {
        int sel = idx >> 6;
        int h = idx & 63;
        const float* cb = conv_b + (sel ? 128 : 0);
        const float* lw = lin_w + (sel ? 2 * 128 * 64 : 0) + h;
        float s = lin_b[(sel ? 2 * 64 : 0) + h];
        for (int k = 0; k < 64; ++k) s += cb[k] * lw[k * 64];
        fused[1024 + idx] = s;
    }
    // probs (1152..1163): softmax(attention)
    if (tid == 0) {
        float m = attention[0];
        for (int t = 1; t < TD; ++t) m = fmaxf(m, attention[t]);
        float e[TD], sum = 0.f;
        for (int t = 0; t < TD; ++t) { e[t] = __expf(attention[t] - m); sum += e[t]; }
        for (int t = 0; t < TD; ++t) fused[1152 + t] = e[t] / sum;
    }
}

__global__ void k_deg_init(float* __restrict__ deg) {
    int i = blockIdx.x * blockDim.x + threadIdx.x;
    if (i < NN) deg[i] = 1.0f;   // self-loop weight
}

__global__ void k_deg_accum(const int* __restrict__ ei, const float* __restrict__ w,
                            float* __restrict__ deg) {
    int e = blockIdx.x * blockDim.x + threadIdx.x;
    if (e < EE) atomicAdd(&deg[ei[EE + e]], w[e]);
}

__global__ void k_dinv(const float* __restrict__ deg, float* __restrict__ dinv) {
    int i = blockIdx.x * blockDim.x + threadIdx.x;
    if (i < NN) dinv[i] = rsqrtf(deg[i]);   // deg >= 1 always
}

// agg[n][j] = dinv[n]^2 * x[n][j]  (self-loop term; also serves as the zeroing pass)
__global__ void k_agg_init(const float* __restrict__ x, const float* __restrict__ dinv,
                           float* __restrict__ agg) {
    unsigned idx = blockIdx.x * blockDim.x + threadIdx.x;
    if (idx >= (unsigned)NN * FT) return;
    unsigned n = idx / FT;
    float d = dinv[n];
    agg[idx] = d * d * x[idx];
}

__global__ void k_coeff(const int* __restrict__ ei, const float* __restrict__ w,
                        const float* __restrict__ dinv, float* __restrict__ coeff) {
    int e = blockIdx.x * blockDim.x + threadIdx.x;
    if (e < EE) coeff[e] = dinv[ei[e]] * w[e] * dinv[ei[EE + e]];
}

// one thread per (edge, element): 153.6M f32 atomics
__global__ void k_scatter(const float* __restrict__ x, const int* __restrict__ ei,
                          const float* __restrict__ coeff, float* __restrict__ agg) {
    unsigned idx = blockIdx.x * blockDim.x + threadIdx.x;
    if (idx >= (unsigned)EE * FT) return;
    unsigned e = idx / FT;
    unsigned j = idx - e * FT;
    int s = ei[e], d = ei[EE + e];
    atomicAdd(&agg[(unsigned)d * FT + j], coeff[e] * x[(unsigned)s * FT + j]);
}

__global__ __launch_bounds__(64) void k_node(const float* __restrict__ agg,
                                             const float* __restrict__ fused,
                                             const float* __restrict__ cls_w,
                                             const float* __restrict__ cls_b,
                                             float* __restrict__ out) {
    __shared__ float sW[1164 + 768 + 12];
    for (int i = threadIdx.x; i < 1164; i += 64) sW[i] = fused[i];
    for (int i = threadIdx.x; i < 768; i += 64) sW[1164 + i] = cls_w[i];
    if (threadIdx.x < 12) sW[1164 + 768 + threadIdx.x] = cls_b[threadIdx.x];
    __syncthreads();
    int n = blockIdx.x * 64 + threadIdx.x;
    if (n >= NN) return;

    float r[FT];
    const float4* ap = (const float4*)(agg + (size_t)n * FT);
#pragma unroll
    for (int i = 0; i < FT / 4; ++i) {
        float4 v = ap[i];
        r[4 * i] = v.x; r[4 * i + 1] = v.y; r[4 * i + 2] = v.z; r[4 * i + 3] = v.w;
    }
    float outT[TD];
#pragma unroll
    for (int t = 0; t < TD; ++t) outT[t] = 0.f;

    const float* Wzz = sW;
    const float* Whh = sW + 512;
    const float* bzz = sW + 1024;
    const float* bhh = sW + 1088;
    const float* probs = sW + 1152;
    const float* cw = sW + 1164;

    for (int h = 0; h < HD; ++h) {
        float wz[FD], wh[FD];
#pragma unroll
        for (int f = 0; f < FD; ++f) { wz[f] = Wzz[f * 64 + h]; wh[f] = Whh[f * 64 + h]; }
        float acc = 0.f;
#pragma unroll
        for (int t = 0; t < TD; ++t) {
            float z = bzz[h], hh = bhh[h];
#pragma unroll
            for (int f = 0; f < FD; ++f) {
                float v = r[f * TD + t];
                z += v * wz[f];
                hh += v * wh[f];
            }
            float Z = 1.f / (1.f + __expf(-z));            // sigmoid
            float Ht = 1.f - 2.f / (1.f + __expf(2.f * hh)); // tanh
            acc += probs[t] * (1.f - Z) * Ht;
        }
        float rel = fmaxf(acc, 0.f);
#pragma unroll
        for (int t = 0; t < TD; ++t) outT[t] += rel * cw[h * TD + t];
    }
    float* op = out + (size_t)n * TD;
#pragma unroll
    for (int t = 0; t < TD; ++t) op[t] = outT[t] + sW[1164 + 768 + t];
}

extern "C" void kernel_launch(void* const* d_in, const int* in_sizes, int n_in,
                              void* d_out, int out_size, void* d_ws, size_t ws_size,
                              hipStream_t stream) {
    const float* x         = (const float*)d_in[0];
    const int*   ei        = (const int*)d_in[1];
    const float* w         = (const float*)d_in[2];
    const float* conv_w    = (const float*)d_in[3];
    const float* conv_b    = (const float*)d_in[4];
    const float* lin_w     = (const float*)d_in[5];
    const float* lin_b     = (const float*)d_in[6];
    const float* attention = (const float*)d_in[7];
    const float* cls_w     = (const float*)d_in[8];
    const float* cls_b     = (const float*)d_in[9];
    float* ws  = (float*)d_ws;
    float* out = (float*)d_out;

    float* deg   = ws + OFF_DEG;
    float* dinv  = ws + OFF_DINV;
    float* coeff = ws + OFF_COEFF;
    float* agg   = ws + OFF_AGG;
    float* fused = ws + OFF_FUSED;

    k_precompute<<<1, 256, 0, stream>>>(conv_w, conv_b, lin_w, lin_b, attention, fused);
    k_deg_init<<<(NN + 255) / 256, 256, 0, stream>>>(deg);
    k_deg_accum<<<(EE + 255) / 256, 256, 0, stream>>>(ei, w, deg);
    k_dinv<<<(NN + 255) / 256, 256, 0, stream>>>(deg, dinv);
    k_agg_init<<<(NN * FT + 255) / 256, 256, 0, stream>>>(x, dinv, agg);
    k_coeff<<<(EE + 255) / 256, 256, 0, stream>>>(ei, w, dinv, coeff);
    {
        unsigned total = (unsigned)EE * FT;   // 153,600,000
        k_scatter<<<(total + 255) / 256, 256, 0, stream>>>(x, ei, coeff, agg);
    }
    k_node<<<(NN + 63) / 64, 64, 0, stream>>>(agg, fused, cls_w, cls_b, out);
}

// Round 2
// 436.639 us; speedup vs baseline: 1.8675x; 1.8675x over previous
//
#include <hip/hip_runtime.h>
#include <math.h>

#define NN 50000
#define FD 8
#define TD 12
#define HD 64
#define FT 96            // FD*TD floats per node
#define EE 1600000
#define NB 196           // ceil(NN/256) scan blocks

// Workspace layout in 4-byte units:
#define OFF_DEG    0                       // float[NN]
#define OFF_DINV   (NN)                    // float[NN]
#define OFF_COUNTS (2*NN)                  // int[NN]   (destroyed by k_fill)
#define OFF_ROWST  (3*NN)                  // int[NN+1]
#define OFF_PART   (4*NN + 16)             // int[256]
#define OFF_PARTEX (4*NN + 16 + 256)       // int[256]
#define OFF_EDATA  (4*NN + 1024)           // int2[EE] = 2*EE units (8B aligned)
#define OFF_AGG    (OFF_EDATA + 2*EE)      // float[NN*FT] (16B aligned)
#define OFF_FUSED  (OFF_AGG + NN*FT)       // float[1164]
// total ~= 8.2M units ~= 32.8 MB

__global__ void k_precompute(const float* __restrict__ conv_w,
                             const float* __restrict__ conv_b,
                             const float* __restrict__ lin_w,
                             const float* __restrict__ lin_b,
                             const float* __restrict__ attention,
                             float* __restrict__ fused) {
    int tid = threadIdx.x;
    // Wzz (0..511): f,h -> sum_k conv_w[f][k]    * lin_w[0][k][h]
    // Whh (512..1023):    sum_k conv_w[f][128+k] * lin_w[2][k][h]
    for (int idx = tid; idx < 1024; idx += blockDim.x) {
        int sel = idx >> 9;
        int f = (idx & 511) >> 6;
        int h = idx & 63;
        const float* cw = conv_w + f * 192 + (sel ? 128 : 0);
        const float* lw = lin_w + (sel ? 2 * 128 * 64 : 0) + h;
        float s = 0.f;
        for (int k = 0; k < 64; ++k) s += cw[k] * lw[k * 64];
        fused[idx] = s;
    }
    // bzz (1024..1087), bhh (1088..1151)
    for (int idx = tid; idx < 128; idx += blockDim.x) {
        int sel = idx >> 6;
        int h = idx & 63;
        const float* cb = conv_b + (sel ? 128 : 0);
        const float* lw = lin_w + (sel ? 2 * 128 * 64 : 0) + h;
        float s = lin_b[(sel ? 2 * 64 : 0) + h];
        for (int k = 0; k < 64; ++k) s += cb[k] * lw[k * 64];
        fused[1024 + idx] = s;
    }
    // probs (1152..1163): softmax(attention)
    if (tid == 0) {
        float m = attention[0];
        for (int t = 1; t < TD; ++t) m = fmaxf(m, attention[t]);
        float e[TD], sum = 0.f;
        for (int t = 0; t < TD; ++t) { e[t] = __expf(attention[t] - m); sum += e[t]; }
        for (int t = 0; t < TD; ++t) fused[1152 + t] = e[t] / sum;
    }
}

__global__ void k_init(float* __restrict__ deg, int* __restrict__ counts) {
    int i = blockIdx.x * blockDim.x + threadIdx.x;
    if (i < NN) { deg[i] = 1.0f; counts[i] = 0; }   // self-loop weight 1
}

// one pass over edges: weighted degree + dst histogram
__global__ void k_edge1(const int* __restrict__ ei, const float* __restrict__ w,
                        float* __restrict__ deg, int* __restrict__ counts) {
    int e = blockIdx.x * blockDim.x + threadIdx.x;
    if (e >= EE) return;
    int d = ei[EE + e];
    atomicAdd(&deg[d], w[e]);
    atomicAdd(&counts[d], 1);
}

__global__ void k_dinv(const float* __restrict__ deg, float* __restrict__ dinv) {
    int i = blockIdx.x * blockDim.x + threadIdx.x;
    if (i < NN) dinv[i] = rsqrtf(deg[i]);   // deg >= 1 always
}

__global__ void k_scan1(const int* __restrict__ counts, int* __restrict__ partial) {
    __shared__ int s[256];
    int i = blockIdx.x * 256 + threadIdx.x;
    s[threadIdx.x] = (i < NN) ? counts[i] : 0;
    __syncthreads();
    for (int off = 128; off > 0; off >>= 1) {
        if (threadIdx.x < off) s[threadIdx.x] += s[threadIdx.x + off];
        __syncthreads();
    }
    if (threadIdx.x == 0) partial[blockIdx.x] = s[0];
}

__global__ void k_scan2(const int* __restrict__ partial, int* __restrict__ partialex) {
    __shared__ int s[256];
    int v = (threadIdx.x < NB) ? partial[threadIdx.x] : 0;
    s[threadIdx.x] = v;
    __syncthreads();
    for (int off = 1; off < 256; off <<= 1) {
        int t = (threadIdx.x >= off) ? s[threadIdx.x - off] : 0;
        __syncthreads();
        s[threadIdx.x] += t;
        __syncthreads();
    }
    partialex[threadIdx.x] = s[threadIdx.x] - v;   // exclusive
}

__global__ void k_scan3(const int* __restrict__ counts, const int* __restrict__ partialex,
                        int* __restrict__ rowstart) {
    __shared__ int s[256];
    int i = blockIdx.x * 256 + threadIdx.x;
    int v = (i < NN) ? counts[i] : 0;
    s[threadIdx.x] = v;
    __syncthreads();
    for (int off = 1; off < 256; off <<= 1) {
        int t = (threadIdx.x >= off) ? s[threadIdx.x - off] : 0;
        __syncthreads();
        s[threadIdx.x] += t;
        __syncthreads();
    }
    int excl = s[threadIdx.x] - v + partialex[blockIdx.x];
    if (i < NN) rowstart[i] = excl;
    if (i == NN - 1) rowstart[NN] = excl + v;   // == EE
}

// claim slots by decrementing counts (counts ends at 0; rebuilt every launch)
__global__ void k_fill(const int* __restrict__ ei, const float* __restrict__ w,
                       const float* __restrict__ dinv, const int* __restrict__ rowstart,
                       int* __restrict__ counts, int2* __restrict__ edata) {
    int e = blockIdx.x * blockDim.x + threadIdx.x;
    if (e >= EE) return;
    int s = ei[e], d = ei[EE + e];
    float c = dinv[s] * w[e] * dinv[d];
    int pos = atomicSub(&counts[d], 1) - 1;
    edata[rowstart[d] + pos] = make_int2(s, __float_as_int(c));
}

// thread = (node, float4-chunk). 24 lanes share a node -> 384B coalesced x reads.
__global__ __launch_bounds__(256) void k_gather(const float* __restrict__ x,
                                                const float* __restrict__ dinv,
                                                const int* __restrict__ rowstart,
                                                const int2* __restrict__ edata,
                                                float* __restrict__ agg) {
    unsigned t = blockIdx.x * 256u + threadIdx.x;
    if (t >= (unsigned)NN * 24u) return;
    unsigned n = t / 24u;
    unsigned c = t - n * 24u;
    const float4* x4 = (const float4*)x;
    float dv = dinv[n], dd = dv * dv;
    float4 a = x4[n * 24u + c];
    a.x *= dd; a.y *= dd; a.z *= dd; a.w *= dd;
    int rs = rowstart[n], re = rowstart[n + 1];
    for (int k = rs; k < re; ++k) {
        int2 p = edata[k];
        float co = __int_as_float(p.y);
        float4 xv = x4[(unsigned)p.x * 24u + c];
        a.x += co * xv.x; a.y += co * xv.y; a.z += co * xv.z; a.w += co * xv.w;
    }
    ((float4*)agg)[n * 24u + c] = a;
}

__global__ __launch_bounds__(256) void k_node(const float* __restrict__ agg,
                                              const float* __restrict__ fused,
                                              const float* __restrict__ cls_w,
                                              const float* __restrict__ cls_b,
                                              float* __restrict__ out) {
    __shared__ float sW[1164 + 768 + 12];
    for (int i = threadIdx.x; i < 1164 + 768; i += 256)
        sW[i] = (i < 1164) ? fused[i] : cls_w[i - 1164];
    if (threadIdx.x < 12) sW[1164 + 768 + threadIdx.x] = cls_b[threadIdx.x];
    __syncthreads();
    int n = blockIdx.x * 256 + threadIdx.x;
    if (n >= NN) return;

    float r[FT];
    const float4* ap = (const float4*)(agg + (size_t)n * FT);
#pragma unroll
    for (int i = 0; i < FT / 4; ++i) {
        float4 v = ap[i];
        r[4 * i] = v.x; r[4 * i + 1] = v.y; r[4 * i + 2] = v.z; r[4 * i + 3] = v.w;
    }
    float outT[TD];
#pragma unroll
    for (int t = 0; t < TD; ++t) outT[t] = 0.f;

    const float* Wzz = sW;
    const float* Whh = sW + 512;
    const float* bzz = sW + 1024;
    const float* bhh = sW + 1088;
    const float* probs = sW + 1152;
    const float* cw = sW + 1164;

    for (int h = 0; h < HD; ++h) {
        float wz[FD], wh[FD];
#pragma unroll
        for (int f = 0; f < FD; ++f) { wz[f] = Wzz[f * 64 + h]; wh[f] = Whh[f * 64 + h]; }
        float acc = 0.f;
#pragma unroll
        for (int t = 0; t < TD; ++t) {
            float z = bzz[h], hh = bhh[h];
#pragma unroll
            for (int f = 0; f < FD; ++f) {
                float v = r[f * TD + t];
                z += v * wz[f];
                hh += v * wh[f];
            }
            float Z = 1.f / (1.f + __expf(-z));              // sigmoid
            float Ht = 1.f - 2.f / (1.f + __expf(2.f * hh)); // tanh
            acc += probs[t] * (1.f - Z) * Ht;
        }
        float rel = fmaxf(acc, 0.f);
#pragma unroll
        for (int t = 0; t < TD; ++t) outT[t] += rel * cw[h * TD + t];
    }
    float* op = out + (size_t)n * TD;
#pragma unroll
    for (int t = 0; t < TD; ++t) op[t] = outT[t] + sW[1164 + 768 + t];
}

extern "C" void kernel_launch(void* const* d_in, const int* in_sizes, int n_in,
                              void* d_out, int out_size, void* d_ws, size_t ws_size,
                              hipStream_t stream) {
    const float* x         = (const float*)d_in[0];
    const int*   ei        = (const int*)d_in[1];
    const float* w         = (const float*)d_in[2];
    const float* conv_w    = (const float*)d_in[3];
    const float* conv_b    = (const float*)d_in[4];
    const float* lin_w     = (const float*)d_in[5];
    const float* lin_b     = (const float*)d_in[6];
    const float* attention = (const float*)d_in[7];
    const float* cls_w     = (const float*)d_in[8];
    const float* cls_b     = (const float*)d_in[9];
    float* ws  = (float*)d_ws;
    float* out = (float*)d_out;

    float* deg      = ws + OFF_DEG;
    float* dinv     = ws + OFF_DINV;
    int*   counts   = (int*)(ws + OFF_COUNTS);
    int*   rowstart = (int*)(ws + OFF_ROWST);
    int*   partial  = (int*)(ws + OFF_PART);
    int*   partialex= (int*)(ws + OFF_PARTEX);
    int2*  edata    = (int2*)(ws + OFF_EDATA);
    float* agg      = ws + OFF_AGG;
    float* fused    = ws + OFF_FUSED;

    k_precompute<<<1, 256, 0, stream>>>(conv_w, conv_b, lin_w, lin_b, attention, fused);
    k_init<<<(NN + 255) / 256, 256, 0, stream>>>(deg, counts);
    k_edge1<<<(EE + 255) / 256, 256, 0, stream>>>(ei, w, deg, counts);
    k_dinv<<<(NN + 255) / 256, 256, 0, stream>>>(deg, dinv);
    k_scan1<<<NB, 256, 0, stream>>>(counts, partial);
    k_scan2<<<1, 256, 0, stream>>>(partial, partialex);
    k_scan3<<<NB, 256, 0, stream>>>(counts, partialex, rowstart);
    k_fill<<<(EE + 255) / 256, 256, 0, stream>>>(ei, w, dinv, rowstart, counts, edata);
    {
        unsigned total = (unsigned)NN * 24u;   // 1.2M threads
        k_gather<<<(total + 255) / 256, 256, 0, stream>>>(x, dinv, rowstart, edata, agg);
    }
    k_node<<<(NN + 255) / 256, 256, 0, stream>>>(agg, fused, cls_w, cls_b, out);
}

// Round 3
// 366.979 us; speedup vs baseline: 2.2220x; 1.1898x over previous
//
#include <hip/hip_runtime.h>
#include <math.h>

#define NN 50000
#define FD 8
#define TD 12
#define HD 64
#define FT 96            // FD*TD floats per node
#define EE 1600000
#define NB 196           // ceil(NN/256) scan blocks
#define FIX 16777216.0f  // 2^24 fixed-point scale for weighted degree

// Workspace layout in 4-byte units:
#define OFF_PACK   0                       // ull[NN]: hi=count, lo=sum(w)*2^24
#define OFF_DINV   (2*NN)                  // float[NN]
#define OFF_ROWST  (3*NN)                  // int[NN+1]
#define OFF_PART   (4*NN + 16)             // int[256]
#define OFF_PARTEX (4*NN + 16 + 256)       // int[256]
#define OFF_EDATA  (4*NN + 1024)           // int2[EE] = 2*EE units (8B aligned)
#define OFF_AGG    (OFF_EDATA + 2*EE)      // float[NN*FT]
#define OFF_FUSED  (OFF_AGG + NN*FT)       // float[1164]

__global__ void k_precompute(const float* __restrict__ conv_w,
                             const float* __restrict__ conv_b,
                             const float* __restrict__ lin_w,
                             const float* __restrict__ lin_b,
                             const float* __restrict__ attention,
                             float* __restrict__ fused) {
    int tid = threadIdx.x;
    // Wzz (0..511): f,h -> sum_k conv_w[f][k]    * lin_w[0][k][h]
    // Whh (512..1023):    sum_k conv_w[f][128+k] * lin_w[2][k][h]
    for (int idx = tid; idx < 1024; idx += blockDim.x) {
        int sel = idx >> 9;
        int f = (idx & 511) >> 6;
        int h = idx & 63;
        const float* cw = conv_w + f * 192 + (sel ? 128 : 0);
        const float* lw = lin_w + (sel ? 2 * 128 * 64 : 0) + h;
        float s = 0.f;
        for (int k = 0; k < 64; ++k) s += cw[k] * lw[k * 64];
        fused[idx] = s;
    }
    // bzz (1024..1087), bhh (1088..1151)
    for (int idx = tid; idx < 128; idx += blockDim.x) {
        int sel = idx >> 6;
        int h = idx & 63;
        const float* cb = conv_b + (sel ? 128 : 0);
        const float* lw = lin_w + (sel ? 2 * 128 * 64 : 0) + h;
        float s = lin_b[(sel ? 2 * 64 : 0) + h];
        for (int k = 0; k < 64; ++k) s += cb[k] * lw[k * 64];
        fused[1024 + idx] = s;
    }
    // probs (1152..1163): softmax(attention)
    if (tid == 0) {
        float m = attention[0];
        for (int t = 1; t < TD; ++t) m = fmaxf(m, attention[t]);
        float e[TD], sum = 0.f;
        for (int t = 0; t < TD; ++t) { e[t] = __expf(attention[t] - m); sum += e[t]; }
        for (int t = 0; t < TD; ++t) fused[1152 + t] = e[t] / sum;
    }
}

__global__ void k_init(unsigned long long* __restrict__ pack) {
    int i = blockIdx.x * blockDim.x + threadIdx.x;
    if (i < NN) pack[i] = 0ULL;
}

// one packed 8B atomic per edge: count (hi) + fixed-point weight sum (lo)
__global__ void k_edge1(const int* __restrict__ ei, const float* __restrict__ w,
                        unsigned long long* __restrict__ pack) {
    int e = blockIdx.x * blockDim.x + threadIdx.x;
    if (e >= EE) return;
    int d = ei[EE + e];
    unsigned fx = (unsigned)(w[e] * FIX);
    atomicAdd(&pack[d], (1ULL << 32) | (unsigned long long)fx);
}

// block-sum of counts + dinv computation fused
__global__ void k_scan1(const unsigned long long* __restrict__ pack,
                        int* __restrict__ partial, float* __restrict__ dinv) {
    __shared__ int s[256];
    int i = blockIdx.x * 256 + threadIdx.x;
    int c = 0;
    if (i < NN) {
        unsigned long long p = pack[i];
        c = (int)(p >> 32);
        float deg = 1.0f + (float)(unsigned)(p & 0xFFFFFFFFull) * (1.0f / FIX);
        dinv[i] = rsqrtf(deg);   // self-loop weight 1 included
    }
    s[threadIdx.x] = c;
    __syncthreads();
    for (int off = 128; off > 0; off >>= 1) {
        if (threadIdx.x < off) s[threadIdx.x] += s[threadIdx.x + off];
        __syncthreads();
    }
    if (threadIdx.x == 0) partial[blockIdx.x] = s[0];
}

__global__ void k_scan2(const int* __restrict__ partial, int* __restrict__ partialex) {
    __shared__ int s[256];
    int v = (threadIdx.x < NB) ? partial[threadIdx.x] : 0;
    s[threadIdx.x] = v;
    __syncthreads();
    for (int off = 1; off < 256; off <<= 1) {
        int t = (threadIdx.x >= off) ? s[threadIdx.x - off] : 0;
        __syncthreads();
        s[threadIdx.x] += t;
        __syncthreads();
    }
    partialex[threadIdx.x] = s[threadIdx.x] - v;   // exclusive
}

__global__ void k_scan3(const unsigned long long* __restrict__ pack,
                        const int* __restrict__ partialex, int* __restrict__ rowstart) {
    __shared__ int s[256];
    int i = blockIdx.x * 256 + threadIdx.x;
    int v = (i < NN) ? (int)(pack[i] >> 32) : 0;
    s[threadIdx.x] = v;
    __syncthreads();
    for (int off = 1; off < 256; off <<= 1) {
        int t = (threadIdx.x >= off) ? s[threadIdx.x - off] : 0;
        __syncthreads();
        s[threadIdx.x] += t;
        __syncthreads();
    }
    int excl = s[threadIdx.x] - v + partialex[blockIdx.x];
    if (i < NN) rowstart[i] = excl;
    if (i == NN - 1) rowstart[NN] = excl + v;   // == EE
}

// claim slots by decrementing the packed count (hi 32 bits); store (src, dinv[s]*w)
__global__ void k_fill(const int* __restrict__ ei, const float* __restrict__ w,
                       const float* __restrict__ dinv, const int* __restrict__ rowstart,
                       unsigned long long* __restrict__ pack, int2* __restrict__ edata) {
    int e = blockIdx.x * blockDim.x + threadIdx.x;
    if (e >= EE) return;
    int s = ei[e], d = ei[EE + e];
    float c = dinv[s] * w[e];   // dinv[d] applied once per node in k_gather
    unsigned long long old = atomicAdd(&pack[d], (unsigned long long)(-(1LL << 32)));
    int pos = (int)(old >> 32) - 1;
    edata[rowstart[d] + pos] = make_int2(s, __float_as_int(c));
}

// thread = (node, float4-chunk). 24 lanes share a node -> 384B coalesced x reads.
__global__ __launch_bounds__(256) void k_gather(const float* __restrict__ x,
                                                const float* __restrict__ dinv,
                                                const int* __restrict__ rowstart,
                                                const int2* __restrict__ edata,
                                                float* __restrict__ agg) {
    unsigned t = blockIdx.x * 256u + threadIdx.x;
    if (t >= (unsigned)NN * 24u) return;
    unsigned n = t / 24u;
    unsigned c = t - n * 24u;
    const float4* x4 = (const float4*)x;
    float dv = dinv[n];
    float4 a = x4[n * 24u + c];
    a.x *= dv; a.y *= dv; a.z *= dv; a.w *= dv;   // dinv[n]*x[n]
    int rs = rowstart[n], re = rowstart[n + 1];
    for (int k = rs; k < re; ++k) {
        int2 p = edata[k];
        float co = __int_as_float(p.y);           // dinv[s]*w
        float4 xv = x4[(unsigned)p.x * 24u + c];
        a.x += co * xv.x; a.y += co * xv.y; a.z += co * xv.z; a.w += co * xv.w;
    }
    // final *dinv[n]: gives dinv^2*x[n] + dinv[n]*sum(dinv[s]*w*x[s])
    a.x *= dv; a.y *= dv; a.z *= dv; a.w *= dv;
    ((float4*)agg)[n * 24u + c] = a;
}

__global__ __launch_bounds__(256) void k_node(const float* __restrict__ agg,
                                              const float* __restrict__ fused,
                                              const float* __restrict__ cls_w,
                                              const float* __restrict__ cls_b,
                                              float* __restrict__ out) {
    __shared__ float sW[1164 + 768 + 12];
    for (int i = threadIdx.x; i < 1164 + 768; i += 256)
        sW[i] = (i < 1164) ? fused[i] : cls_w[i - 1164];
    if (threadIdx.x < 12) sW[1164 + 768 + threadIdx.x] = cls_b[threadIdx.x];
    __syncthreads();
    int n = blockIdx.x * 256 + threadIdx.x;
    if (n >= NN) return;

    float r[FT];
    const float4* ap = (const float4*)(agg + (size_t)n * FT);
#pragma unroll
    for (int i = 0; i < FT / 4; ++i) {
        float4 v = ap[i];
        r[4 * i] = v.x; r[4 * i + 1] = v.y; r[4 * i + 2] = v.z; r[4 * i + 3] = v.w;
    }
    float outT[TD];
#pragma unroll
    for (int t = 0; t < TD; ++t) outT[t] = 0.f;

    const float* Wzz = sW;
    const float* Whh = sW + 512;
    const float* bzz = sW + 1024;
    const float* bhh = sW + 1088;
    const float* probs = sW + 1152;
    const float* cw = sW + 1164;

    for (int h = 0; h < HD; ++h) {
        float wz[FD], wh[FD];
#pragma unroll
        for (int f = 0; f < FD; ++f) { wz[f] = Wzz[f * 64 + h]; wh[f] = Whh[f * 64 + h]; }
        float acc = 0.f;
#pragma unroll
        for (int t = 0; t < TD; ++t) {
            float z = bzz[h], hh = bhh[h];
#pragma unroll
            for (int f = 0; f < FD; ++f) {
                float v = r[f * TD + t];
                z += v * wz[f];
                hh += v * wh[f];
            }
            float Z = 1.f / (1.f + __expf(-z));              // sigmoid
            float Ht = 1.f - 2.f / (1.f + __expf(2.f * hh)); // tanh
            acc += probs[t] * (1.f - Z) * Ht;
        }
        float rel = fmaxf(acc, 0.f);
#pragma unroll
        for (int t = 0; t < TD; ++t) outT[t] += rel * cw[h * TD + t];
    }
    float* op = out + (size_t)n * TD;
#pragma unroll
    for (int t = 0; t < TD; ++t) op[t] = outT[t] + sW[1164 + 768 + t];
}

extern "C" void kernel_launch(void* const* d_in, const int* in_sizes, int n_in,
                              void* d_out, int out_size, void* d_ws, size_t ws_size,
                              hipStream_t stream) {
    const float* x         = (const float*)d_in[0];
    const int*   ei        = (const int*)d_in[1];
    const float* w         = (const float*)d_in[2];
    const float* conv_w    = (const float*)d_in[3];
    const float* conv_b    = (const float*)d_in[4];
    const float* lin_w     = (const float*)d_in[5];
    const float* lin_b     = (const float*)d_in[6];
    const float* attention = (const float*)d_in[7];
    const float* cls_w     = (const float*)d_in[8];
    const float* cls_b     = (const float*)d_in[9];
    float* ws  = (float*)d_ws;
    float* out = (float*)d_out;

    unsigned long long* pack = (unsigned long long*)(ws + OFF_PACK);
    float* dinv      = ws + OFF_DINV;
    int*   rowstart  = (int*)(ws + OFF_ROWST);
    int*   partial   = (int*)(ws + OFF_PART);
    int*   partialex = (int*)(ws + OFF_PARTEX);
    int2*  edata     = (int2*)(ws + OFF_EDATA);
    float* agg       = ws + OFF_AGG;
    float* fused     = ws + OFF_FUSED;

    k_precompute<<<1, 256, 0, stream>>>(conv_w, conv_b, lin_w, lin_b, attention, fused);
    k_init<<<(NN + 255) / 256, 256, 0, stream>>>(pack);
    k_edge1<<<(EE + 255) / 256, 256, 0, stream>>>(ei, w, pack);
    k_scan1<<<NB, 256, 0, stream>>>(pack, partial, dinv);
    k_scan2<<<1, 256, 0, stream>>>(partial, partialex);
    k_scan3<<<NB, 256, 0, stream>>>(pack, partialex, rowstart);
    k_fill<<<(EE + 255) / 256, 256, 0, stream>>>(ei, w, dinv, rowstart, pack, edata);
    {
        unsigned total = (unsigned)NN * 24u;   // 1.2M threads
        k_gather<<<(total + 255) / 256, 256, 0, stream>>>(x, dinv, rowstart, edata, agg);
    }
    k_node<<<(NN + 255) / 256, 256, 0, stream>>>(agg, fused, cls_w, cls_b, out);
}